// Round 4
// baseline (2267.617 us; speedup 1.0000x reference)
//
#include <hip/hip_runtime.h>

#define NPTS 1000000
#define NVOX 200000
#define EPSV 1e-5f

// ---- ws layout (4-byte words) ----
// zeroed each launch:
#define OFF_CNT    0          // 200000 ints  (per-voxel counts)
#define OFF_STATS  200000     // 32 floats: [0..3]=Sx..Sw [4..7]=Sx2.. [8..10]=Sc [11..13]=Sc2
                              //            [14..16]=Sn [17..19]=Sn2 [20..22]=Sum c*m^2
#define OFF_SUMH1  200032     // 64
#define OFF_SUMQ1  200096     // 64
#define OFF_SUMH2  200160     // 64
#define OFF_SUMQ2  200224     // 64
#define ZERO_WORDS 200288
// non-zeroed (fully overwritten every launch):
#define OFF_BASE   200288     // 200000 ints (CSR: after k_fill, base[v] = end offset of voxel v)
#define OFF_BSUM   400288     // 512
#define OFF_BOFF   400800     // 512
#define OFF_PIDX   401312     // 1000000 ints
#define OFF_VOX    1401312    // 800000 floats {mx,my,mz,cnt}
#define OFF_WF     2201312    // 832  (BN0-folded w1)
#define OFF_BF     2202144    // 64
#define OFF_WF2    2202208    // 832  (BN0+BN1-folded w1)
#define OFF_BF2    2203040    // 64
#define OFF_S2     2203104    // 64
#define OFF_T2     2203168    // 64
#define WS_WORDS   2203232

#define SCAN_B 512
#define NSCAN ((NVOX + SCAN_B - 1) / SCAN_B)   // 391

__device__ __forceinline__ float bcast(float x, int k) {
    return __int_as_float(__builtin_amdgcn_readlane(__float_as_int(x), k));
}
__device__ __forceinline__ float wave_red(float x) {
#pragma unroll
    for (int o = 32; o > 0; o >>= 1) x += __shfl_down(x, o);
    return x;
}

// ---- macro-generated straight-line register code (no arrays => no spill) ----
#define REP13(M) M(0) M(1) M(2) M(3) M(4) M(5) M(6) M(7) M(8) M(9) M(10) M(11) M(12)
#define REP64(M) M(0) M(1) M(2) M(3) M(4) M(5) M(6) M(7) M(8) M(9) \
 M(10) M(11) M(12) M(13) M(14) M(15) M(16) M(17) M(18) M(19) \
 M(20) M(21) M(22) M(23) M(24) M(25) M(26) M(27) M(28) M(29) \
 M(30) M(31) M(32) M(33) M(34) M(35) M(36) M(37) M(38) M(39) \
 M(40) M(41) M(42) M(43) M(44) M(45) M(46) M(47) M(48) M(49) \
 M(50) M(51) M(52) M(53) M(54) M(55) M(56) M(57) M(58) M(59) \
 M(60) M(61) M(62) M(63)

#define DECL_W1(J)  float w1c_##J = Wfp[(J)*64 + lane];
#define DECL_W2(K)  float w2c_##K = w2[(K)*64 + lane];
#define DECL_W3(K)  float w3c_##K = w3[(K)*64 + lane];

// features f0..f12 from point p; expects float4 vs (voxel mean) in scope
#define FEAT_BODY \
    float4 pt = pts[p]; \
    int g0 = gind[3*p], g1 = gind[3*p+1], g2 = gind[3*p+2]; \
    float f0 = pt.x, f1 = pt.y, f2 = pt.z, f3 = pt.w; \
    float f4 = pt.x - vs.x, f5 = pt.y - vs.y, f6 = pt.z - vs.z; \
    float f7 = pt.x - ((float)g0 * 0.2f - 51.2f); \
    float f8 = pt.y - ((float)g1 * 0.2f - 51.2f); \
    float f9 = pt.z - ((float)g2 * 0.2f - 4.0f); \
    float f10 = nor[3*p], f11 = nor[3*p+1], f12 = nor[3*p+2];

#define FEAT_GATHER float4 vs = vox4[cinv[p]]; FEAT_BODY

#define L1EXPR (bc + ((((f0*w1c_0 + f1*w1c_1) + (f2*w1c_2 + f3*w1c_3)) \
              + ((f4*w1c_4 + f5*w1c_5) + (f6*w1c_6 + f7*w1c_7))) \
              + (((f8*w1c_8 + f9*w1c_9) + (f10*w1c_10 + f11*w1c_11)) \
              + f12*w1c_12)))

#define L2G(A,B,C,D) ha += bcast(r,A)*w2c_##A; hb += bcast(r,B)*w2c_##B; \
                     hc += bcast(r,C)*w2c_##C; hd += bcast(r,D)*w2c_##D;
#define L2ALL L2G(0,1,2,3) L2G(4,5,6,7) L2G(8,9,10,11) L2G(12,13,14,15) \
  L2G(16,17,18,19) L2G(20,21,22,23) L2G(24,25,26,27) L2G(28,29,30,31) \
  L2G(32,33,34,35) L2G(36,37,38,39) L2G(40,41,42,43) L2G(44,45,46,47) \
  L2G(48,49,50,51) L2G(52,53,54,55) L2G(56,57,58,59) L2G(60,61,62,63)

#define L3G(A,B,C,D) ya += bcast(m,A)*w3c_##A; yb += bcast(m,B)*w3c_##B; \
                     yc += bcast(m,C)*w3c_##C; yd += bcast(m,D)*w3c_##D;
#define L3ALL L3G(0,1,2,3) L3G(4,5,6,7) L3G(8,9,10,11) L3G(12,13,14,15) \
  L3G(16,17,18,19) L3G(20,21,22,23) L3G(24,25,26,27) L3G(28,29,30,31) \
  L3G(32,33,34,35) L3G(36,37,38,39) L3G(40,41,42,43) L3G(44,45,46,47) \
  L3G(48,49,50,51) L3G(52,53,54,55) L3G(56,57,58,59) L3G(60,61,62,63)

// ---------------- counts ----------------
__global__ __launch_bounds__(256) void k_count(
    const int* __restrict__ cinv, int* __restrict__ cnt)
{
    int i = blockIdx.x * 256 + threadIdx.x;
    if (i < NPTS) atomicAdd(&cnt[cinv[i]], 1);
}

// ---------------- scan ----------------
__global__ __launch_bounds__(SCAN_B) void k_scan1(
    const int* __restrict__ cnt, int* __restrict__ base, int* __restrict__ bsum)
{
    __shared__ int sd[SCAN_B];
    int t = threadIdx.x;
    int v = blockIdx.x * SCAN_B + t;
    int x = (v < NVOX) ? cnt[v] : 0;
    sd[t] = x;
    __syncthreads();
    for (int o = 1; o < SCAN_B; o <<= 1) {
        int y = (t >= o) ? sd[t - o] : 0;
        __syncthreads();
        sd[t] += y;
        __syncthreads();
    }
    if (v < NVOX) base[v] = sd[t] - x;   // exclusive within block
    if (t == SCAN_B - 1) bsum[blockIdx.x] = sd[t];
}

__global__ __launch_bounds__(SCAN_B) void k_scan2(
    const int* __restrict__ bsum, int* __restrict__ boff)
{
    __shared__ int sd[SCAN_B];
    int t = threadIdx.x;
    int x = (t < NSCAN) ? bsum[t] : 0;
    sd[t] = x;
    __syncthreads();
    for (int o = 1; o < SCAN_B; o <<= 1) {
        int y = (t >= o) ? sd[t - o] : 0;
        __syncthreads();
        sd[t] += y;
        __syncthreads();
    }
    if (t < NSCAN) boff[t] = sd[t] - x;
}

__global__ __launch_bounds__(256) void k_base(
    const int* __restrict__ boff, int* __restrict__ base)
{
    int v = blockIdx.x * 256 + threadIdx.x;
    if (v < NVOX) base[v] += boff[v >> 9];
}

// fill: base[v] self-increments; afterwards base[v] == END offset of voxel v
__global__ __launch_bounds__(256) void k_fill(
    const int* __restrict__ cinv, int* __restrict__ base, int* __restrict__ pidx)
{
    int i = blockIdx.x * 256 + threadIdx.x;
    if (i >= NPTS) return;
    int slot = atomicAdd(&base[cinv[i]], 1);
    pidx[slot] = i;
}

// ---------------- per-voxel means (thread per voxel, no atomics on vox) ------
__global__ __launch_bounds__(256) void k_mean(
    const float4* __restrict__ pts, const int* __restrict__ base,
    const int* __restrict__ pidx, float4* __restrict__ vox4,
    float* __restrict__ stats)
{
    int v = blockIdx.x * 256 + threadIdx.x;
    float cm2x = 0.f, cm2y = 0.f, cm2z = 0.f;
    if (v < NVOX) {
        int st = (v == 0) ? 0 : base[v - 1];
        int en = base[v];
        int c = en - st;
        float sx = 0.f, sy = 0.f, sz = 0.f;
        for (int i = st; i < en; i++) {
            float4 p = pts[pidx[i]];
            sx += p.x; sy += p.y; sz += p.z;
        }
        float fc = (float)c;
        float ic = 1.0f / fmaxf(fc, 1.0f);
        float mx = sx * ic, my = sy * ic, mz = sz * ic;
        vox4[v] = make_float4(mx, my, mz, fc);
        cm2x = fc * mx * mx; cm2y = fc * my * my; cm2z = fc * mz * mz;
    }
    cm2x = wave_red(cm2x); cm2y = wave_red(cm2y); cm2z = wave_red(cm2z);
    if ((threadIdx.x & 63) == 0) {
        atomicAdd(&stats[20], cm2x);
        atomicAdd(&stats[21], cm2y);
        atomicAdd(&stats[22], cm2z);
    }
}

// ---------------- feature first/second moments (20 scalar accumulators) -----
__global__ __launch_bounds__(256) void k_stats0(
    const float4* __restrict__ pts, const float* __restrict__ nor,
    const int* __restrict__ gind, float* __restrict__ stats)
{
    int tid = blockIdx.x * blockDim.x + threadIdx.x;
    int T = gridDim.x * blockDim.x;
    float s0=0,s1=0,s2=0,s3=0, q0=0,q1=0,q2=0,q3=0;
    float sc0=0,sc1=0,sc2=0, qc0=0,qc1=0,qc2=0;
    float sn0=0,sn1=0,sn2=0, qn0=0,qn1=0,qn2=0;
    for (int i = tid; i < NPTS; i += T) {
        float4 p = pts[i];
        int g0 = gind[3*i], g1 = gind[3*i+1], g2 = gind[3*i+2];
        float n0 = nor[3*i], n1 = nor[3*i+1], n2 = nor[3*i+2];
        s0 += p.x; s1 += p.y; s2 += p.z; s3 += p.w;
        q0 += p.x*p.x; q1 += p.y*p.y; q2 += p.z*p.z; q3 += p.w*p.w;
        float c0 = p.x - ((float)g0 * 0.2f - 51.2f);
        float c1 = p.y - ((float)g1 * 0.2f - 51.2f);
        float c2 = p.z - ((float)g2 * 0.2f - 4.0f);
        sc0 += c0; sc1 += c1; sc2 += c2;
        qc0 += c0*c0; qc1 += c1*c1; qc2 += c2*c2;
        sn0 += n0; sn1 += n1; sn2 += n2;
        qn0 += n0*n0; qn1 += n1*n1; qn2 += n2*n2;
    }
    int lane = threadIdx.x & 63;
#define RED1(X, IDX) { float r_ = wave_red(X); if (lane == 0) atomicAdd(&stats[IDX], r_); }
    RED1(s0,0) RED1(s1,1) RED1(s2,2) RED1(s3,3)
    RED1(q0,4) RED1(q1,5) RED1(q2,6) RED1(q3,7)
    RED1(sc0,8) RED1(sc1,9) RED1(sc2,10)
    RED1(qc0,11) RED1(qc1,12) RED1(qc2,13)
    RED1(sn0,14) RED1(sn1,15) RED1(sn2,16)
    RED1(qn0,17) RED1(qn1,18) RED1(qn2,19)
#undef RED1
}

// ---------------- fold BN0 into w1 -> Wf, bf ----------------
__global__ void k3b_fold(
    const float* __restrict__ stats,
    const float* __restrict__ bn0g, const float* __restrict__ bn0b,
    const float* __restrict__ w1, const float* __restrict__ b1,
    float* __restrict__ Wf, float* __restrict__ bfv)
{
    int c = threadIdx.x;  // 64
    const float invN = 1.0f / (float)NPTS;
    float m[13], vr[13];
    for (int j = 0; j < 4; j++)  { m[j] = stats[j] * invN;       vr[j] = stats[4+j] * invN - m[j]*m[j]; }
    for (int j = 4; j < 7; j++)  { m[j] = 0.f;                   vr[j] = stats[j] * invN - stats[16+j] * invN; }
    for (int j = 7; j < 10; j++) { m[j] = stats[1+j] * invN;     vr[j] = stats[4+j] * invN - m[j]*m[j]; }
    for (int j = 10; j < 13; j++){ m[j] = stats[4+j] * invN;     vr[j] = stats[7+j] * invN - m[j]*m[j]; }
    float bacc = b1[c];
    for (int j = 0; j < 13; j++) {
        float s = bn0g[j] * rsqrtf(vr[j] + EPSV);
        float t = bn0b[j] - m[j] * s;
        Wf[j*64 + c] = s * w1[j*64 + c];
        bacc += t * w1[j*64 + c];
    }
    bfv[c] = bacc;
}

// ---------------- BN1 stats (layer-1 only, wave per point) ----------------
__global__ __launch_bounds__(256, 4) void k2b_stats1(
    const float4* __restrict__ pts, const float* __restrict__ nor,
    const int* __restrict__ gind, const int* __restrict__ cinv,
    const float4* __restrict__ vox4,
    const float* __restrict__ Wfp, const float* __restrict__ bfv,
    float* __restrict__ sumH, float* __restrict__ sumQ)
{
    int lane = threadIdx.x & 63;
    int wid = blockIdx.x * 4 + (threadIdx.x >> 6);
    int nw = gridDim.x * 4;
    REP13(DECL_W1)
    float bc = bfv[lane];
    float sh = 0.f, sq = 0.f;
    for (int p = wid; p < NPTS; p += nw) {
        FEAT_GATHER
        float a = L1EXPR;
        sh += a; sq += a * a;
    }
    atomicAdd(&sumH[lane], sh);
    atomicAdd(&sumQ[lane], sq);
}

// ---------------- fold BN1 -> Wf2, bf2 ----------------
__global__ void k3c_fold(
    const float* __restrict__ sumH, const float* __restrict__ sumQ,
    const float* __restrict__ bn1g, const float* __restrict__ bn1b,
    const float* __restrict__ Wf, const float* __restrict__ bfv,
    float* __restrict__ Wf2, float* __restrict__ bf2)
{
    int c = threadIdx.x;  // 64
    const float invN = 1.0f / (float)NPTS;
    float mn = sumH[c] * invN;
    float vr = sumQ[c] * invN - mn * mn;
    float s = bn1g[c] * rsqrtf(vr + EPSV);
    float t = bn1b[c] - mn * s;
    for (int j = 0; j < 13; j++) Wf2[j*64 + c] = s * Wf[j*64 + c];
    bf2[c] = s * bfv[c] + t;
}

// ---------------- BN2 stats (full layer 1+2, wave per point) ----------------
__global__ __launch_bounds__(256, 3) void k4_stats2(
    const float4* __restrict__ pts, const float* __restrict__ nor,
    const int* __restrict__ gind, const int* __restrict__ cinv,
    const float4* __restrict__ vox4,
    const float* __restrict__ Wfp, const float* __restrict__ bfv,
    const float* __restrict__ w2, const float* __restrict__ b2,
    float* __restrict__ sumH, float* __restrict__ sumQ)
{
    int lane = threadIdx.x & 63;
    int wid = blockIdx.x * 4 + (threadIdx.x >> 6);
    int nw = gridDim.x * 4;
    REP13(DECL_W1)
    float bc = bfv[lane];
    REP64(DECL_W2)
    float b2c = b2[lane];
    float sh = 0.f, sq = 0.f;
    for (int p = wid; p < NPTS; p += nw) {
        FEAT_GATHER
        float r = fmaxf(L1EXPR, 0.f);
        float ha = b2c, hb = 0.f, hc = 0.f, hd = 0.f;
        L2ALL
        float h = (ha + hb) + (hc + hd);
        sh += h; sq += h * h;
    }
    atomicAdd(&sumH[lane], sh);
    atomicAdd(&sumQ[lane], sq);
}

// ---------------- finalize BN2 ----------------
__global__ void k5_bn2(
    const float* __restrict__ sumH, const float* __restrict__ sumQ,
    const float* __restrict__ bn2g, const float* __restrict__ bn2b,
    float* __restrict__ s2, float* __restrict__ t2)
{
    const float invN = 1.0f / (float)NPTS;
    int c = threadIdx.x;
    float mn = sumH[c] * invN;
    float vr = sumQ[c] * invN - mn * mn;
    float s = bn2g[c] * rsqrtf(vr + EPSV);
    s2[c] = s; t2[c] = bn2b[c] - mn * s;
}

// ---------------- main forward + per-voxel sum (wave per voxel, CSR) --------
__global__ __launch_bounds__(256, 3) void k6_gather(
    const float4* __restrict__ pts, const float* __restrict__ nor,
    const int* __restrict__ gind,
    const int* __restrict__ base, const int* __restrict__ pidx,
    const float4* __restrict__ vox4,
    const float* __restrict__ Wfp, const float* __restrict__ bfv,
    const float* __restrict__ w2, const float* __restrict__ b2,
    const float* __restrict__ s2, const float* __restrict__ t2,
    float* __restrict__ out)
{
    int lane = threadIdx.x & 63;
    int wid = blockIdx.x * 4 + (threadIdx.x >> 6);
    int nw = gridDim.x * 4;
    REP13(DECL_W1)
    float bc = bfv[lane];
    REP64(DECL_W2)
    float b2c = b2[lane];
    float s2c = s2[lane], t2c = t2[lane];

    for (int v = wid; v < NVOX; v += nw) {
        int st = (v == 0) ? 0 : base[v - 1];
        int en = base[v];
        float4 vs = vox4[v];
        float accz = 0.f;
        for (int ii = st; ii < en; ii++) {
            int p = pidx[ii];
            FEAT_BODY
            float r = fmaxf(L1EXPR, 0.f);
            float ha = b2c, hb = 0.f, hc = 0.f, hd = 0.f;
            L2ALL
            float h = (ha + hb) + (hc + hd);
            accz += fmaxf(s2c * h + t2c, 0.f);
        }
        out[(size_t)v * 64 + lane] = accz;
    }
}

// ---------------- mean + w3 matmul + bias (in-place on d_out) ----------------
__global__ __launch_bounds__(256, 4) void k7_final(
    const float4* __restrict__ vox4, const float* __restrict__ w3,
    const float* __restrict__ b3, float* __restrict__ out)
{
    int lane = threadIdx.x & 63;
    int wid = blockIdx.x * 4 + (threadIdx.x >> 6);
    int nw = gridDim.x * 4;
    REP64(DECL_W3)
    float b3c = b3[lane];
    for (int v = wid; v < NVOX; v += nw) {
        float cnt = vox4[v].w;
        float* row = out + (size_t)v * 64;
        if (cnt > 0.5f) {
            float m = row[lane] / cnt;
            float ya = b3c, yb = 0.f, yc = 0.f, yd = 0.f;
            L3ALL
            row[lane] = (ya + yb) + (yc + yd);
        } else {
            row[lane] = 0.f;
        }
    }
}

extern "C" void kernel_launch(void* const* d_in, const int* in_sizes, int n_in,
                              void* d_out, int out_size, void* d_ws, size_t ws_size,
                              hipStream_t stream) {
    const float4* pts  = (const float4*)d_in[0];
    const float*  nor  = (const float*)d_in[1];
    const int*    gind = (const int*)d_in[2];
    const int*    cinv = (const int*)d_in[3];
    const float*  bn0g = (const float*)d_in[4];
    const float*  bn0b = (const float*)d_in[5];
    const float*  w1   = (const float*)d_in[6];
    const float*  b1   = (const float*)d_in[7];
    const float*  bn1g = (const float*)d_in[8];
    const float*  bn1b = (const float*)d_in[9];
    const float*  w2   = (const float*)d_in[10];
    const float*  b2   = (const float*)d_in[11];
    const float*  bn2g = (const float*)d_in[12];
    const float*  bn2b = (const float*)d_in[13];
    const float*  w3   = (const float*)d_in[14];
    const float*  b3   = (const float*)d_in[15];

    float* ws    = (float*)d_ws;
    float* out   = (float*)d_out;
    int*   cnt   = (int*)(ws + OFF_CNT);
    float* stats = ws + OFF_STATS;
    float* sumH1 = ws + OFF_SUMH1;
    float* sumQ1 = ws + OFF_SUMQ1;
    float* sumH2 = ws + OFF_SUMH2;
    float* sumQ2 = ws + OFF_SUMQ2;
    int*   base  = (int*)(ws + OFF_BASE);
    int*   bsum  = (int*)(ws + OFF_BSUM);
    int*   boff  = (int*)(ws + OFF_BOFF);
    int*   pidx  = (int*)(ws + OFF_PIDX);
    float4* vox4 = (float4*)(ws + OFF_VOX);
    float* Wf    = ws + OFF_WF;
    float* bfv   = ws + OFF_BF;
    float* Wf2   = ws + OFF_WF2;
    float* bf2   = ws + OFF_BF2;
    float* s2    = ws + OFF_S2;
    float* t2    = ws + OFF_T2;

    hipMemsetAsync(d_ws, 0, (size_t)ZERO_WORDS * 4, stream);

    k_count<<<(NPTS + 255) / 256, 256, 0, stream>>>(cinv, cnt);
    k_scan1<<<NSCAN, SCAN_B, 0, stream>>>(cnt, base, bsum);
    k_scan2<<<1, SCAN_B, 0, stream>>>(bsum, boff);
    k_base<<<(NVOX + 255) / 256, 256, 0, stream>>>(boff, base);
    k_fill<<<(NPTS + 255) / 256, 256, 0, stream>>>(cinv, base, pidx);
    k_mean<<<(NVOX + 255) / 256, 256, 0, stream>>>(pts, base, pidx, vox4, stats);
    k_stats0<<<1024, 256, 0, stream>>>(pts, nor, gind, stats);
    k3b_fold<<<1, 64, 0, stream>>>(stats, bn0g, bn0b, w1, b1, Wf, bfv);
    k2b_stats1<<<2048, 256, 0, stream>>>(pts, nor, gind, cinv, vox4, Wf, bfv, sumH1, sumQ1);
    k3c_fold<<<1, 64, 0, stream>>>(sumH1, sumQ1, bn1g, bn1b, Wf, bfv, Wf2, bf2);
    k4_stats2<<<2048, 256, 0, stream>>>(pts, nor, gind, cinv, vox4, Wf2, bf2, w2, b2, sumH2, sumQ2);
    k5_bn2<<<1, 64, 0, stream>>>(sumH2, sumQ2, bn2g, bn2b, s2, t2);
    k6_gather<<<4096, 256, 0, stream>>>(pts, nor, gind, base, pidx, vox4,
                                        Wf2, bf2, w2, b2, s2, t2, out);
    k7_final<<<1024, 256, 0, stream>>>(vox4, w3, b3, out);
}

// Round 5
// 1410.662 us; speedup vs baseline: 1.6075x; 1.6075x over previous
//
#include <hip/hip_runtime.h>

#define NPTS 1000000
#define NVOX 200000
#define EPSV 1e-5f

#define SB0 256    // k_stats0 blocks
#define KB1 512    // k2b blocks
#define KB2 512    // k4 blocks
#define NMB ((NVOX + 255) / 256)   // 782 (k_mean blocks)

// ---- ws layout (4-byte words) ----
// zeroed each launch:
#define OFF_CNT    0          // 200000 ints (per-voxel counts)
#define ZERO_WORDS 200000
// fully overwritten every launch (no zeroing needed):
#define OFF_BASE   200000     // 200000 ints (after k_fill: base[v] = END offset of voxel v)
#define OFF_BSUM   400000     // 512
#define OFF_BOFF   400512     // 512
#define OFF_PIDX   401024     // 1000000 ints
#define OFF_VOX    1401024    // 800000 floats {mx,my,mz,cnt}
#define OFF_P0     2201024    // SB0*20 = 5120   (k_stats0 block partials)
#define OFF_PM     2206144    // NMB*4  = 3128   (k_mean cm2 block partials)
#define OFF_PH1    2209272    // KB1*64 = 32768
#define OFF_PQ1    2242040    // 32768
#define OFF_PH2    2274808    // KB2*64 = 32768
#define OFF_PQ2    2307576    // 32768
#define OFF_WF     2340344    // 832 (BN0-folded w1)
#define OFF_BF     2341176    // 64
#define OFF_WF2    2341240    // 832 (BN0+BN1-folded w1)
#define OFF_BF2    2342072    // 64
#define OFF_S2     2342136    // 64
#define OFF_T2     2342200    // 64
#define WS_WORDS   2342264

#define SCAN_B 512
#define NSCAN ((NVOX + SCAN_B - 1) / SCAN_B)   // 391

__device__ __forceinline__ float bcast(float x, int k) {
    return __int_as_float(__builtin_amdgcn_readlane(__float_as_int(x), k));
}
__device__ __forceinline__ float wave_red(float x) {
#pragma unroll
    for (int o = 32; o > 0; o >>= 1) x += __shfl_down(x, o);
    return x;
}

// ---- macro-generated straight-line register code (no arrays => no spill) ----
#define REP13(M) M(0) M(1) M(2) M(3) M(4) M(5) M(6) M(7) M(8) M(9) M(10) M(11) M(12)
#define REP64(M) M(0) M(1) M(2) M(3) M(4) M(5) M(6) M(7) M(8) M(9) \
 M(10) M(11) M(12) M(13) M(14) M(15) M(16) M(17) M(18) M(19) \
 M(20) M(21) M(22) M(23) M(24) M(25) M(26) M(27) M(28) M(29) \
 M(30) M(31) M(32) M(33) M(34) M(35) M(36) M(37) M(38) M(39) \
 M(40) M(41) M(42) M(43) M(44) M(45) M(46) M(47) M(48) M(49) \
 M(50) M(51) M(52) M(53) M(54) M(55) M(56) M(57) M(58) M(59) \
 M(60) M(61) M(62) M(63)

#define DECL_W1(J)  float w1c_##J = Wfp[(J)*64 + lane];
#define DECL_W2(K)  float w2c_##K = w2[(K)*64 + lane];
#define DECL_W3(K)  float w3c_##K = w3[(K)*64 + lane];

// features f0..f12 from point p; expects float4 vs (voxel mean) in scope
#define FEAT_BODY \
    float4 pt = pts[p]; \
    int g0 = gind[3*p], g1 = gind[3*p+1], g2 = gind[3*p+2]; \
    float f0 = pt.x, f1 = pt.y, f2 = pt.z, f3 = pt.w; \
    float f4 = pt.x - vs.x, f5 = pt.y - vs.y, f6 = pt.z - vs.z; \
    float f7 = pt.x - ((float)g0 * 0.2f - 51.2f); \
    float f8 = pt.y - ((float)g1 * 0.2f - 51.2f); \
    float f9 = pt.z - ((float)g2 * 0.2f - 4.0f); \
    float f10 = nor[3*p], f11 = nor[3*p+1], f12 = nor[3*p+2];

#define FEAT_GATHER float4 vs = vox4[cinv[p]]; FEAT_BODY

#define L1EXPR (bc + ((((f0*w1c_0 + f1*w1c_1) + (f2*w1c_2 + f3*w1c_3)) \
              + ((f4*w1c_4 + f5*w1c_5) + (f6*w1c_6 + f7*w1c_7))) \
              + (((f8*w1c_8 + f9*w1c_9) + (f10*w1c_10 + f11*w1c_11)) \
              + f12*w1c_12)))

#define L2G(A,B,C,D) ha += bcast(r,A)*w2c_##A; hb += bcast(r,B)*w2c_##B; \
                     hc += bcast(r,C)*w2c_##C; hd += bcast(r,D)*w2c_##D;
#define L2ALL L2G(0,1,2,3) L2G(4,5,6,7) L2G(8,9,10,11) L2G(12,13,14,15) \
  L2G(16,17,18,19) L2G(20,21,22,23) L2G(24,25,26,27) L2G(28,29,30,31) \
  L2G(32,33,34,35) L2G(36,37,38,39) L2G(40,41,42,43) L2G(44,45,46,47) \
  L2G(48,49,50,51) L2G(52,53,54,55) L2G(56,57,58,59) L2G(60,61,62,63)

#define L3G(A,B,C,D) ya += bcast(m,A)*w3c_##A; yb += bcast(m,B)*w3c_##B; \
                     yc += bcast(m,C)*w3c_##C; yd += bcast(m,D)*w3c_##D;
#define L3ALL L3G(0,1,2,3) L3G(4,5,6,7) L3G(8,9,10,11) L3G(12,13,14,15) \
  L3G(16,17,18,19) L3G(20,21,22,23) L3G(24,25,26,27) L3G(28,29,30,31) \
  L3G(32,33,34,35) L3G(36,37,38,39) L3G(40,41,42,43) L3G(44,45,46,47) \
  L3G(48,49,50,51) L3G(52,53,54,55) L3G(56,57,58,59) L3G(60,61,62,63)

// ---------------- counts (scattered atomics over 200K addrs: fine) ----------
__global__ __launch_bounds__(256) void k_count(
    const int* __restrict__ cinv, int* __restrict__ cnt)
{
    int i = blockIdx.x * 256 + threadIdx.x;
    if (i < NPTS) atomicAdd(&cnt[cinv[i]], 1);
}

// ---------------- scan ----------------
__global__ __launch_bounds__(SCAN_B) void k_scan1(
    const int* __restrict__ cnt, int* __restrict__ base, int* __restrict__ bsum)
{
    __shared__ int sd[SCAN_B];
    int t = threadIdx.x;
    int v = blockIdx.x * SCAN_B + t;
    int x = (v < NVOX) ? cnt[v] : 0;
    sd[t] = x;
    __syncthreads();
    for (int o = 1; o < SCAN_B; o <<= 1) {
        int y = (t >= o) ? sd[t - o] : 0;
        __syncthreads();
        sd[t] += y;
        __syncthreads();
    }
    if (v < NVOX) base[v] = sd[t] - x;
    if (t == SCAN_B - 1) bsum[blockIdx.x] = sd[t];
}

__global__ __launch_bounds__(SCAN_B) void k_scan2(
    const int* __restrict__ bsum, int* __restrict__ boff)
{
    __shared__ int sd[SCAN_B];
    int t = threadIdx.x;
    int x = (t < NSCAN) ? bsum[t] : 0;
    sd[t] = x;
    __syncthreads();
    for (int o = 1; o < SCAN_B; o <<= 1) {
        int y = (t >= o) ? sd[t - o] : 0;
        __syncthreads();
        sd[t] += y;
        __syncthreads();
    }
    if (t < NSCAN) boff[t] = sd[t] - x;
}

__global__ __launch_bounds__(256) void k_base(
    const int* __restrict__ boff, int* __restrict__ base)
{
    int v = blockIdx.x * 256 + threadIdx.x;
    if (v < NVOX) base[v] += boff[v >> 9];
}

// fill: base[v] self-increments; afterwards base[v] == END offset of voxel v
__global__ __launch_bounds__(256) void k_fill(
    const int* __restrict__ cinv, int* __restrict__ base, int* __restrict__ pidx)
{
    int i = blockIdx.x * 256 + threadIdx.x;
    if (i >= NPTS) return;
    int slot = atomicAdd(&base[cinv[i]], 1);
    pidx[slot] = i;
}

// ---------------- per-voxel means; cm2 partials per block (no hot atomics) --
__global__ __launch_bounds__(256, 2) void k_mean(
    const float4* __restrict__ pts, const int* __restrict__ base,
    const int* __restrict__ pidx, float4* __restrict__ vox4,
    float* __restrict__ PM)
{
    int v = blockIdx.x * 256 + threadIdx.x;
    float cm2x = 0.f, cm2y = 0.f, cm2z = 0.f;
    if (v < NVOX) {
        int st = (v == 0) ? 0 : base[v - 1];
        int en = base[v];
        int c = en - st;
        float sx = 0.f, sy = 0.f, sz = 0.f;
        for (int i = st; i < en; i++) {
            float4 p = pts[pidx[i]];
            sx += p.x; sy += p.y; sz += p.z;
        }
        float fc = (float)c;
        float ic = 1.0f / fmaxf(fc, 1.0f);
        float mx = sx * ic, my = sy * ic, mz = sz * ic;
        vox4[v] = make_float4(mx, my, mz, fc);
        cm2x = fc * mx * mx; cm2y = fc * my * my; cm2z = fc * mz * mz;
    }
    cm2x = wave_red(cm2x); cm2y = wave_red(cm2y); cm2z = wave_red(cm2z);
    __shared__ float red[4][3];
    int w = threadIdx.x >> 6, lane = threadIdx.x & 63;
    if (lane == 0) { red[w][0] = cm2x; red[w][1] = cm2y; red[w][2] = cm2z; }
    __syncthreads();
    if (threadIdx.x < 3)
        PM[blockIdx.x * 4 + threadIdx.x] =
            red[0][threadIdx.x] + red[1][threadIdx.x] + red[2][threadIdx.x] + red[3][threadIdx.x];
}

// ---------------- feature first/second moments -> per-block partials --------
__global__ __launch_bounds__(256, 2) void k_stats0(
    const float4* __restrict__ pts, const float* __restrict__ nor,
    const int* __restrict__ gind, float* __restrict__ P0)
{
    int tid = blockIdx.x * 256 + threadIdx.x;
    const int T = SB0 * 256;
    float s0=0,s1=0,s2=0,s3=0, q0=0,q1=0,q2=0,q3=0;
    float sc0=0,sc1=0,sc2=0, qc0=0,qc1=0,qc2=0;
    float sn0=0,sn1=0,sn2=0, qn0=0,qn1=0,qn2=0;
    for (int i = tid; i < NPTS; i += T) {
        float4 p = pts[i];
        int g0 = gind[3*i], g1 = gind[3*i+1], g2 = gind[3*i+2];
        float n0 = nor[3*i], n1 = nor[3*i+1], n2 = nor[3*i+2];
        s0 += p.x; s1 += p.y; s2 += p.z; s3 += p.w;
        q0 += p.x*p.x; q1 += p.y*p.y; q2 += p.z*p.z; q3 += p.w*p.w;
        float c0 = p.x - ((float)g0 * 0.2f - 51.2f);
        float c1 = p.y - ((float)g1 * 0.2f - 51.2f);
        float c2 = p.z - ((float)g2 * 0.2f - 4.0f);
        sc0 += c0; sc1 += c1; sc2 += c2;
        qc0 += c0*c0; qc1 += c1*c1; qc2 += c2*c2;
        sn0 += n0; sn1 += n1; sn2 += n2;
        qn0 += n0*n0; qn1 += n1*n1; qn2 += n2*n2;
    }
    int w = threadIdx.x >> 6, lane = threadIdx.x & 63;
    __shared__ float red[4][20];
    s0 = wave_red(s0); s1 = wave_red(s1); s2 = wave_red(s2); s3 = wave_red(s3);
    q0 = wave_red(q0); q1 = wave_red(q1); q2 = wave_red(q2); q3 = wave_red(q3);
    sc0 = wave_red(sc0); sc1 = wave_red(sc1); sc2 = wave_red(sc2);
    qc0 = wave_red(qc0); qc1 = wave_red(qc1); qc2 = wave_red(qc2);
    sn0 = wave_red(sn0); sn1 = wave_red(sn1); sn2 = wave_red(sn2);
    qn0 = wave_red(qn0); qn1 = wave_red(qn1); qn2 = wave_red(qn2);
    if (lane == 0) {
        red[w][0]=s0;  red[w][1]=s1;  red[w][2]=s2;  red[w][3]=s3;
        red[w][4]=q0;  red[w][5]=q1;  red[w][6]=q2;  red[w][7]=q3;
        red[w][8]=sc0; red[w][9]=sc1; red[w][10]=sc2;
        red[w][11]=qc0; red[w][12]=qc1; red[w][13]=qc2;
        red[w][14]=sn0; red[w][15]=sn1; red[w][16]=sn2;
        red[w][17]=qn0; red[w][18]=qn1; red[w][19]=qn2;
    }
    __syncthreads();
    int t = threadIdx.x;
    if (t < 20)
        P0[blockIdx.x * 20 + t] = red[0][t] + red[1][t] + red[2][t] + red[3][t];
}

// ---------------- reduce partials + fold BN0 into w1 -> Wf, bf ----------------
__global__ void k3b_fold(
    const float* __restrict__ P0, const float* __restrict__ PM,
    const float* __restrict__ bn0g, const float* __restrict__ bn0b,
    const float* __restrict__ w1, const float* __restrict__ b1,
    float* __restrict__ Wf, float* __restrict__ bfv)
{
    __shared__ float st[23];
    int t = threadIdx.x;  // 64 threads = 1 wave
    for (int j = 0; j < 20; j++) {
        float s = 0.f;
        for (int b = t; b < SB0; b += 64) s += P0[b * 20 + j];
        s = wave_red(s);
        if (t == 0) st[j] = s;
    }
    for (int j = 0; j < 3; j++) {
        float s = 0.f;
        for (int b = t; b < NMB; b += 64) s += PM[b * 4 + j];
        s = wave_red(s);
        if (t == 0) st[20 + j] = s;
    }
    __syncthreads();
    const float invN = 1.0f / (float)NPTS;
    float m[13], vr[13];
    for (int j = 0; j < 4; j++)  { m[j] = st[j] * invN;   vr[j] = st[4+j] * invN - m[j]*m[j]; }
    for (int j = 4; j < 7; j++)  { m[j] = 0.f;            vr[j] = st[j] * invN - st[16+j] * invN; }
    for (int j = 7; j < 10; j++) { m[j] = st[1+j] * invN; vr[j] = st[4+j] * invN - m[j]*m[j]; }
    for (int j = 10; j < 13; j++){ m[j] = st[4+j] * invN; vr[j] = st[7+j] * invN - m[j]*m[j]; }
    float bacc = b1[t];
    for (int j = 0; j < 13; j++) {
        float s = bn0g[j] * rsqrtf(vr[j] + EPSV);
        float tt = bn0b[j] - m[j] * s;
        Wf[j*64 + t] = s * w1[j*64 + t];
        bacc += tt * w1[j*64 + t];
    }
    bfv[t] = bacc;
}

// ---------------- BN1 stats (layer-1 only) -> per-block partials ------------
__global__ __launch_bounds__(256, 2) void k2b_stats1(
    const float4* __restrict__ pts, const float* __restrict__ nor,
    const int* __restrict__ gind, const int* __restrict__ cinv,
    const float4* __restrict__ vox4,
    const float* __restrict__ Wfp, const float* __restrict__ bfv,
    float* __restrict__ PH, float* __restrict__ PQ)
{
    int lane = threadIdx.x & 63;
    int w = threadIdx.x >> 6;
    int wid = blockIdx.x * 4 + w;
    int nw = KB1 * 4;
    REP13(DECL_W1)
    float bc = bfv[lane];
    float sh = 0.f, sq = 0.f;
    for (int p = wid; p < NPTS; p += nw) {
        FEAT_GATHER
        float a = L1EXPR;
        sh += a; sq += a * a;
    }
    __shared__ float LH[4][64], LQ[4][64];
    LH[w][lane] = sh; LQ[w][lane] = sq;
    __syncthreads();
    if (w == 0) {
        PH[blockIdx.x * 64 + lane] = LH[0][lane] + LH[1][lane] + LH[2][lane] + LH[3][lane];
        PQ[blockIdx.x * 64 + lane] = LQ[0][lane] + LQ[1][lane] + LQ[2][lane] + LQ[3][lane];
    }
}

// ---------------- reduce + fold BN1 -> Wf2, bf2 ----------------
__global__ __launch_bounds__(256) void k3c_fold(
    const float* __restrict__ PH, const float* __restrict__ PQ,
    const float* __restrict__ bn1g, const float* __restrict__ bn1b,
    const float* __restrict__ Wf, const float* __restrict__ bfv,
    float* __restrict__ Wf2, float* __restrict__ bf2)
{
    __shared__ float LH[4][64], LQ[4][64];
    int c = threadIdx.x & 63, g = threadIdx.x >> 6;
    float sH = 0.f, sQ = 0.f;
    for (int b = g; b < KB1; b += 4) { sH += PH[b*64 + c]; sQ += PQ[b*64 + c]; }
    LH[g][c] = sH; LQ[g][c] = sQ;
    __syncthreads();
    if (g == 0) {
        const float invN = 1.0f / (float)NPTS;
        float mn = (LH[0][c] + LH[1][c] + LH[2][c] + LH[3][c]) * invN;
        float vr = (LQ[0][c] + LQ[1][c] + LQ[2][c] + LQ[3][c]) * invN - mn * mn;
        float s = bn1g[c] * rsqrtf(vr + EPSV);
        float t = bn1b[c] - mn * s;
        for (int j = 0; j < 13; j++) Wf2[j*64 + c] = s * Wf[j*64 + c];
        bf2[c] = s * bfv[c] + t;
    }
}

// ---------------- BN2 stats (layer 1+2) -> per-block partials ---------------
__global__ __launch_bounds__(256, 2) void k4_stats2(
    const float4* __restrict__ pts, const float* __restrict__ nor,
    const int* __restrict__ gind, const int* __restrict__ cinv,
    const float4* __restrict__ vox4,
    const float* __restrict__ Wfp, const float* __restrict__ bfv,
    const float* __restrict__ w2, const float* __restrict__ b2,
    float* __restrict__ PH, float* __restrict__ PQ)
{
    int lane = threadIdx.x & 63;
    int w = threadIdx.x >> 6;
    int wid = blockIdx.x * 4 + w;
    int nw = KB2 * 4;
    REP13(DECL_W1)
    float bc = bfv[lane];
    REP64(DECL_W2)
    float b2c = b2[lane];
    float sh = 0.f, sq = 0.f;
    for (int p = wid; p < NPTS; p += nw) {
        FEAT_GATHER
        float r = fmaxf(L1EXPR, 0.f);
        float ha = b2c, hb = 0.f, hc = 0.f, hd = 0.f;
        L2ALL
        float h = (ha + hb) + (hc + hd);
        sh += h; sq += h * h;
    }
    __shared__ float LH[4][64], LQ[4][64];
    LH[w][lane] = sh; LQ[w][lane] = sq;
    __syncthreads();
    if (w == 0) {
        PH[blockIdx.x * 64 + lane] = LH[0][lane] + LH[1][lane] + LH[2][lane] + LH[3][lane];
        PQ[blockIdx.x * 64 + lane] = LQ[0][lane] + LQ[1][lane] + LQ[2][lane] + LQ[3][lane];
    }
}

// ---------------- reduce + finalize BN2 -> s2, t2 ----------------
__global__ __launch_bounds__(256) void k5_bn2(
    const float* __restrict__ PH, const float* __restrict__ PQ,
    const float* __restrict__ bn2g, const float* __restrict__ bn2b,
    float* __restrict__ s2, float* __restrict__ t2)
{
    __shared__ float LH[4][64], LQ[4][64];
    int c = threadIdx.x & 63, g = threadIdx.x >> 6;
    float sH = 0.f, sQ = 0.f;
    for (int b = g; b < KB2; b += 4) { sH += PH[b*64 + c]; sQ += PQ[b*64 + c]; }
    LH[g][c] = sH; LQ[g][c] = sQ;
    __syncthreads();
    if (g == 0) {
        const float invN = 1.0f / (float)NPTS;
        float mn = (LH[0][c] + LH[1][c] + LH[2][c] + LH[3][c]) * invN;
        float vr = (LQ[0][c] + LQ[1][c] + LQ[2][c] + LQ[3][c]) * invN - mn * mn;
        float s = bn2g[c] * rsqrtf(vr + EPSV);
        s2[c] = s; t2[c] = bn2b[c] - mn * s;
    }
}

// ---------------- main forward + per-voxel sum (wave per voxel, CSR) --------
__global__ __launch_bounds__(256, 2) void k6_gather(
    const float4* __restrict__ pts, const float* __restrict__ nor,
    const int* __restrict__ gind,
    const int* __restrict__ base, const int* __restrict__ pidx,
    const float4* __restrict__ vox4,
    const float* __restrict__ Wfp, const float* __restrict__ bfv,
    const float* __restrict__ w2, const float* __restrict__ b2,
    const float* __restrict__ s2, const float* __restrict__ t2,
    float* __restrict__ out)
{
    int lane = threadIdx.x & 63;
    int wid = blockIdx.x * 4 + (threadIdx.x >> 6);
    int nw = gridDim.x * 4;
    REP13(DECL_W1)
    float bc = bfv[lane];
    REP64(DECL_W2)
    float b2c = b2[lane];
    float s2c = s2[lane], t2c = t2[lane];

    for (int v = wid; v < NVOX; v += nw) {
        int st = (v == 0) ? 0 : base[v - 1];
        int en = base[v];
        float4 vs = vox4[v];
        float accz = 0.f;
        for (int ii = st; ii < en; ii++) {
            int p = pidx[ii];
            FEAT_BODY
            float r = fmaxf(L1EXPR, 0.f);
            float ha = b2c, hb = 0.f, hc = 0.f, hd = 0.f;
            L2ALL
            float h = (ha + hb) + (hc + hd);
            accz += fmaxf(s2c * h + t2c, 0.f);
        }
        out[(size_t)v * 64 + lane] = accz;
    }
}

// ---------------- mean + w3 matmul + bias (in-place on d_out) ----------------
__global__ __launch_bounds__(256, 2) void k7_final(
    const float4* __restrict__ vox4, const float* __restrict__ w3,
    const float* __restrict__ b3, float* __restrict__ out)
{
    int lane = threadIdx.x & 63;
    int wid = blockIdx.x * 4 + (threadIdx.x >> 6);
    int nw = gridDim.x * 4;
    REP64(DECL_W3)
    float b3c = b3[lane];
    for (int v = wid; v < NVOX; v += nw) {
        float cnt = vox4[v].w;
        float* row = out + (size_t)v * 64;
        if (cnt > 0.5f) {
            float m = row[lane] / cnt;
            float ya = b3c, yb = 0.f, yc = 0.f, yd = 0.f;
            L3ALL
            row[lane] = (ya + yb) + (yc + yd);
        } else {
            row[lane] = 0.f;
        }
    }
}

extern "C" void kernel_launch(void* const* d_in, const int* in_sizes, int n_in,
                              void* d_out, int out_size, void* d_ws, size_t ws_size,
                              hipStream_t stream) {
    const float4* pts  = (const float4*)d_in[0];
    const float*  nor  = (const float*)d_in[1];
    const int*    gind = (const int*)d_in[2];
    const int*    cinv = (const int*)d_in[3];
    const float*  bn0g = (const float*)d_in[4];
    const float*  bn0b = (const float*)d_in[5];
    const float*  w1   = (const float*)d_in[6];
    const float*  b1   = (const float*)d_in[7];
    const float*  bn1g = (const float*)d_in[8];
    const float*  bn1b = (const float*)d_in[9];
    const float*  w2   = (const float*)d_in[10];
    const float*  b2   = (const float*)d_in[11];
    const float*  bn2g = (const float*)d_in[12];
    const float*  bn2b = (const float*)d_in[13];
    const float*  w3   = (const float*)d_in[14];
    const float*  b3   = (const float*)d_in[15];

    float* ws    = (float*)d_ws;
    float* out   = (float*)d_out;
    int*   cnt   = (int*)(ws + OFF_CNT);
    int*   base  = (int*)(ws + OFF_BASE);
    int*   bsum  = (int*)(ws + OFF_BSUM);
    int*   boff  = (int*)(ws + OFF_BOFF);
    int*   pidx  = (int*)(ws + OFF_PIDX);
    float4* vox4 = (float4*)(ws + OFF_VOX);
    float* P0    = ws + OFF_P0;
    float* PM    = ws + OFF_PM;
    float* PH1   = ws + OFF_PH1;
    float* PQ1   = ws + OFF_PQ1;
    float* PH2   = ws + OFF_PH2;
    float* PQ2   = ws + OFF_PQ2;
    float* Wf    = ws + OFF_WF;
    float* bfv   = ws + OFF_BF;
    float* Wf2   = ws + OFF_WF2;
    float* bf2   = ws + OFF_BF2;
    float* s2    = ws + OFF_S2;
    float* t2    = ws + OFF_T2;

    hipMemsetAsync(d_ws, 0, (size_t)ZERO_WORDS * 4, stream);

    k_count<<<(NPTS + 255) / 256, 256, 0, stream>>>(cinv, cnt);
    k_scan1<<<NSCAN, SCAN_B, 0, stream>>>(cnt, base, bsum);
    k_scan2<<<1, SCAN_B, 0, stream>>>(bsum, boff);
    k_base<<<(NVOX + 255) / 256, 256, 0, stream>>>(boff, base);
    k_fill<<<(NPTS + 255) / 256, 256, 0, stream>>>(cinv, base, pidx);
    k_mean<<<NMB, 256, 0, stream>>>(pts, base, pidx, vox4, PM);
    k_stats0<<<SB0, 256, 0, stream>>>(pts, nor, gind, P0);
    k3b_fold<<<1, 64, 0, stream>>>(P0, PM, bn0g, bn0b, w1, b1, Wf, bfv);
    k2b_stats1<<<KB1, 256, 0, stream>>>(pts, nor, gind, cinv, vox4, Wf, bfv, PH1, PQ1);
    k3c_fold<<<1, 256, 0, stream>>>(PH1, PQ1, bn1g, bn1b, Wf, bfv, Wf2, bf2);
    k4_stats2<<<KB2, 256, 0, stream>>>(pts, nor, gind, cinv, vox4, Wf2, bf2, w2, b2, PH2, PQ2);
    k5_bn2<<<1, 256, 0, stream>>>(PH2, PQ2, bn2g, bn2b, s2, t2);
    k6_gather<<<4096, 256, 0, stream>>>(pts, nor, gind, base, pidx, vox4,
                                        Wf2, bf2, w2, b2, s2, t2, out);
    k7_final<<<1024, 256, 0, stream>>>(vox4, w3, b3, out);
}

// Round 6
// 1335.058 us; speedup vs baseline: 1.6985x; 1.0566x over previous
//
#include <hip/hip_runtime.h>

#define NPTS 1000000
#define NVOX 200000
#define EPSV 1e-5f

#define SB0 256     // k_stats0 blocks
#define KB1 1024    // k2b blocks (4 waves each)
#define KB2 768     // k4 blocks
#define KB6 768     // k6 blocks
#define KB7 768     // k7 blocks
#define NMB ((NVOX + 255) / 256)   // 782 (k_mean blocks)

#define W1CH ((NPTS + KB1*4 - 1) / (KB1*4))   // 245 pts/wave (k2b)
#define W2CH ((NPTS + KB2*4 - 1) / (KB2*4))   // 326 pts/wave (k4)
#define V6CH ((NVOX + KB6*4 - 1) / (KB6*4))   // 66 vox/wave (k6)
#define V7CH ((NVOX + KB7*4 - 1) / (KB7*4))   // 66 vox/wave (k7)

// ---- ws layout (4-byte words) ----
// zeroed each launch:
#define OFF_CNT    0          // 200000 ints (per-voxel counts)
#define ZERO_WORDS 200000
// fully overwritten every launch:
#define OFF_BASE   200000     // 200000 ints (after k_fill: base[v] = END offset of voxel v)
#define OFF_BSUM   400000     // 512
#define OFF_BOFF   400512     // 512
#define OFF_PIDX   401024     // 1000000 ints
#define OFF_VOX    1401024    // 800000 floats {mx,my,mz,cnt}
#define OFF_P0     2201024    // SB0*20 = 5120
#define OFF_PM     2206144    // NMB*4  = 3128
#define OFF_PH1    2209272    // KB1*64 = 65536
#define OFF_PQ1    2274808    // 65536
#define OFF_PH2    2340344    // KB2*64 = 49152
#define OFF_PQ2    2389496    // 49152
#define OFF_WF     2438648    // 832 (BN0-folded w1)
#define OFF_BF     2439480    // 64
#define OFF_WF2    2439544    // 832 (BN0+BN1-folded w1)
#define OFF_BF2    2440376    // 64
#define OFF_S2     2440440    // 64
#define OFF_T2     2440504    // 64
#define WS_WORDS   2440568

#define SCAN_B 512
#define NSCAN ((NVOX + SCAN_B - 1) / SCAN_B)   // 391

__device__ __forceinline__ float bcast(float x, int k) {
    return __int_as_float(__builtin_amdgcn_readlane(__float_as_int(x), k));
}
__device__ __forceinline__ float wave_red(float x) {
#pragma unroll
    for (int o = 32; o > 0; o >>= 1) x += __shfl_down(x, o);
    return x;
}

// ---- macro-generated straight-line register code ----
#define REP13(M) M(0) M(1) M(2) M(3) M(4) M(5) M(6) M(7) M(8) M(9) M(10) M(11) M(12)
#define REP64(M) M(0) M(1) M(2) M(3) M(4) M(5) M(6) M(7) M(8) M(9) \
 M(10) M(11) M(12) M(13) M(14) M(15) M(16) M(17) M(18) M(19) \
 M(20) M(21) M(22) M(23) M(24) M(25) M(26) M(27) M(28) M(29) \
 M(30) M(31) M(32) M(33) M(34) M(35) M(36) M(37) M(38) M(39) \
 M(40) M(41) M(42) M(43) M(44) M(45) M(46) M(47) M(48) M(49) \
 M(50) M(51) M(52) M(53) M(54) M(55) M(56) M(57) M(58) M(59) \
 M(60) M(61) M(62) M(63)

// PIN: opaque the value so LLVM cannot rematerialize the (invariant) load
// inside the loop — R5 profile: without this, VGPR_Count=60 with 77+ live
// weights => all 64 w2 values re-loaded from L1 every point (3x inst bloat).
#define DECL_W1(J)  float w1c_##J = Wfp[(J)*64 + lane]; asm("" : "+v"(w1c_##J));
#define DECL_W2(K)  float w2c_##K = w2[(K)*64 + lane];  asm("" : "+v"(w2c_##K));
#define DECL_W3(K)  float w3c_##K = w3[(K)*64 + lane];  asm("" : "+v"(w3c_##K));

// features f0..f12 from point p; expects float4 vs (voxel mean) in scope
#define FEAT_BODY \
    float4 pt = pts[p]; \
    int g0 = gind[3*p], g1 = gind[3*p+1], g2 = gind[3*p+2]; \
    float f0 = pt.x, f1 = pt.y, f2 = pt.z, f3 = pt.w; \
    float f4 = pt.x - vs.x, f5 = pt.y - vs.y, f6 = pt.z - vs.z; \
    float f7 = pt.x - ((float)g0 * 0.2f - 51.2f); \
    float f8 = pt.y - ((float)g1 * 0.2f - 51.2f); \
    float f9 = pt.z - ((float)g2 * 0.2f - 4.0f); \
    float f10 = nor[3*p], f11 = nor[3*p+1], f12 = nor[3*p+2];

#define FEAT_GATHER float4 vs = vox4[cinv[p]]; FEAT_BODY

#define L1EXPR (bc + ((((f0*w1c_0 + f1*w1c_1) + (f2*w1c_2 + f3*w1c_3)) \
              + ((f4*w1c_4 + f5*w1c_5) + (f6*w1c_6 + f7*w1c_7))) \
              + (((f8*w1c_8 + f9*w1c_9) + (f10*w1c_10 + f11*w1c_11)) \
              + f12*w1c_12)))

#define L2G(A,B,C,D) ha += bcast(r,A)*w2c_##A; hb += bcast(r,B)*w2c_##B; \
                     hc += bcast(r,C)*w2c_##C; hd += bcast(r,D)*w2c_##D;
#define L2ALL L2G(0,1,2,3) L2G(4,5,6,7) L2G(8,9,10,11) L2G(12,13,14,15) \
  L2G(16,17,18,19) L2G(20,21,22,23) L2G(24,25,26,27) L2G(28,29,30,31) \
  L2G(32,33,34,35) L2G(36,37,38,39) L2G(40,41,42,43) L2G(44,45,46,47) \
  L2G(48,49,50,51) L2G(52,53,54,55) L2G(56,57,58,59) L2G(60,61,62,63)

#define L3G(A,B,C,D) ya += bcast(m,A)*w3c_##A; yb += bcast(m,B)*w3c_##B; \
                     yc += bcast(m,C)*w3c_##C; yd += bcast(m,D)*w3c_##D;
#define L3ALL L3G(0,1,2,3) L3G(4,5,6,7) L3G(8,9,10,11) L3G(12,13,14,15) \
  L3G(16,17,18,19) L3G(20,21,22,23) L3G(24,25,26,27) L3G(28,29,30,31) \
  L3G(32,33,34,35) L3G(36,37,38,39) L3G(40,41,42,43) L3G(44,45,46,47) \
  L3G(48,49,50,51) L3G(52,53,54,55) L3G(56,57,58,59) L3G(60,61,62,63)

// ---------------- counts ----------------
__global__ __launch_bounds__(256) void k_count(
    const int* __restrict__ cinv, int* __restrict__ cnt)
{
    int i = blockIdx.x * 256 + threadIdx.x;
    if (i < NPTS) atomicAdd(&cnt[cinv[i]], 1);
}

// ---------------- scan ----------------
__global__ __launch_bounds__(SCAN_B) void k_scan1(
    const int* __restrict__ cnt, int* __restrict__ base, int* __restrict__ bsum)
{
    __shared__ int sd[SCAN_B];
    int t = threadIdx.x;
    int v = blockIdx.x * SCAN_B + t;
    int x = (v < NVOX) ? cnt[v] : 0;
    sd[t] = x;
    __syncthreads();
    for (int o = 1; o < SCAN_B; o <<= 1) {
        int y = (t >= o) ? sd[t - o] : 0;
        __syncthreads();
        sd[t] += y;
        __syncthreads();
    }
    if (v < NVOX) base[v] = sd[t] - x;
    if (t == SCAN_B - 1) bsum[blockIdx.x] = sd[t];
}

__global__ __launch_bounds__(SCAN_B) void k_scan2(
    const int* __restrict__ bsum, int* __restrict__ boff)
{
    __shared__ int sd[SCAN_B];
    int t = threadIdx.x;
    int x = (t < NSCAN) ? bsum[t] : 0;
    sd[t] = x;
    __syncthreads();
    for (int o = 1; o < SCAN_B; o <<= 1) {
        int y = (t >= o) ? sd[t - o] : 0;
        __syncthreads();
        sd[t] += y;
        __syncthreads();
    }
    if (t < NSCAN) boff[t] = sd[t] - x;
}

__global__ __launch_bounds__(256) void k_base(
    const int* __restrict__ boff, int* __restrict__ base)
{
    int v = blockIdx.x * 256 + threadIdx.x;
    if (v < NVOX) base[v] += boff[v >> 9];
}

__global__ __launch_bounds__(256) void k_fill(
    const int* __restrict__ cinv, int* __restrict__ base, int* __restrict__ pidx)
{
    int i = blockIdx.x * 256 + threadIdx.x;
    if (i >= NPTS) return;
    int slot = atomicAdd(&base[cinv[i]], 1);
    pidx[slot] = i;
}

// ---------------- per-voxel means ----------------
__global__ __launch_bounds__(256, 2) void k_mean(
    const float4* __restrict__ pts, const int* __restrict__ base,
    const int* __restrict__ pidx, float4* __restrict__ vox4,
    float* __restrict__ PM)
{
    int v = blockIdx.x * 256 + threadIdx.x;
    float cm2x = 0.f, cm2y = 0.f, cm2z = 0.f;
    if (v < NVOX) {
        int st = (v == 0) ? 0 : base[v - 1];
        int en = base[v];
        int c = en - st;
        float sx = 0.f, sy = 0.f, sz = 0.f;
        for (int i = st; i < en; i++) {
            float4 p = pts[pidx[i]];
            sx += p.x; sy += p.y; sz += p.z;
        }
        float fc = (float)c;
        float ic = 1.0f / fmaxf(fc, 1.0f);
        float mx = sx * ic, my = sy * ic, mz = sz * ic;
        vox4[v] = make_float4(mx, my, mz, fc);
        cm2x = fc * mx * mx; cm2y = fc * my * my; cm2z = fc * mz * mz;
    }
    cm2x = wave_red(cm2x); cm2y = wave_red(cm2y); cm2z = wave_red(cm2z);
    __shared__ float red[4][3];
    int w = threadIdx.x >> 6, lane = threadIdx.x & 63;
    if (lane == 0) { red[w][0] = cm2x; red[w][1] = cm2y; red[w][2] = cm2z; }
    __syncthreads();
    if (threadIdx.x < 3)
        PM[blockIdx.x * 4 + threadIdx.x] =
            red[0][threadIdx.x] + red[1][threadIdx.x] + red[2][threadIdx.x] + red[3][threadIdx.x];
}

// ---------------- feature first/second moments -> per-block partials --------
__global__ __launch_bounds__(256, 2) void k_stats0(
    const float4* __restrict__ pts, const float* __restrict__ nor,
    const int* __restrict__ gind, float* __restrict__ P0)
{
    // contiguous per-thread chunks
    const int T = SB0 * 256;
    const int CH = (NPTS + T - 1) / T;
    int tid = blockIdx.x * 256 + threadIdx.x;
    int i0 = tid * CH, i1 = min(i0 + CH, NPTS);
    float s0=0,s1=0,s2=0,s3=0, q0=0,q1=0,q2=0,q3=0;
    float sc0=0,sc1=0,sc2=0, qc0=0,qc1=0,qc2=0;
    float sn0=0,sn1=0,sn2=0, qn0=0,qn1=0,qn2=0;
    for (int i = i0; i < i1; i++) {
        float4 p = pts[i];
        int g0 = gind[3*i], g1 = gind[3*i+1], g2 = gind[3*i+2];
        float n0 = nor[3*i], n1 = nor[3*i+1], n2 = nor[3*i+2];
        s0 += p.x; s1 += p.y; s2 += p.z; s3 += p.w;
        q0 += p.x*p.x; q1 += p.y*p.y; q2 += p.z*p.z; q3 += p.w*p.w;
        float c0 = p.x - ((float)g0 * 0.2f - 51.2f);
        float c1 = p.y - ((float)g1 * 0.2f - 51.2f);
        float c2 = p.z - ((float)g2 * 0.2f - 4.0f);
        sc0 += c0; sc1 += c1; sc2 += c2;
        qc0 += c0*c0; qc1 += c1*c1; qc2 += c2*c2;
        sn0 += n0; sn1 += n1; sn2 += n2;
        qn0 += n0*n0; qn1 += n1*n1; qn2 += n2*n2;
    }
    int w = threadIdx.x >> 6, lane = threadIdx.x & 63;
    __shared__ float red[4][20];
    s0 = wave_red(s0); s1 = wave_red(s1); s2 = wave_red(s2); s3 = wave_red(s3);
    q0 = wave_red(q0); q1 = wave_red(q1); q2 = wave_red(q2); q3 = wave_red(q3);
    sc0 = wave_red(sc0); sc1 = wave_red(sc1); sc2 = wave_red(sc2);
    qc0 = wave_red(qc0); qc1 = wave_red(qc1); qc2 = wave_red(qc2);
    sn0 = wave_red(sn0); sn1 = wave_red(sn1); sn2 = wave_red(sn2);
    qn0 = wave_red(qn0); qn1 = wave_red(qn1); qn2 = wave_red(qn2);
    if (lane == 0) {
        red[w][0]=s0;  red[w][1]=s1;  red[w][2]=s2;  red[w][3]=s3;
        red[w][4]=q0;  red[w][5]=q1;  red[w][6]=q2;  red[w][7]=q3;
        red[w][8]=sc0; red[w][9]=sc1; red[w][10]=sc2;
        red[w][11]=qc0; red[w][12]=qc1; red[w][13]=qc2;
        red[w][14]=sn0; red[w][15]=sn1; red[w][16]=sn2;
        red[w][17]=qn0; red[w][18]=qn1; red[w][19]=qn2;
    }
    __syncthreads();
    int t = threadIdx.x;
    if (t < 20)
        P0[blockIdx.x * 20 + t] = red[0][t] + red[1][t] + red[2][t] + red[3][t];
}

// ---------------- reduce partials + fold BN0 ----------------
__global__ void k3b_fold(
    const float* __restrict__ P0, const float* __restrict__ PM,
    const float* __restrict__ bn0g, const float* __restrict__ bn0b,
    const float* __restrict__ w1, const float* __restrict__ b1,
    float* __restrict__ Wf, float* __restrict__ bfv)
{
    __shared__ float st[23];
    int t = threadIdx.x;  // 64
    for (int j = 0; j < 20; j++) {
        float s = 0.f;
        for (int b = t; b < SB0; b += 64) s += P0[b * 20 + j];
        s = wave_red(s);
        if (t == 0) st[j] = s;
    }
    for (int j = 0; j < 3; j++) {
        float s = 0.f;
        for (int b = t; b < NMB; b += 64) s += PM[b * 4 + j];
        s = wave_red(s);
        if (t == 0) st[20 + j] = s;
    }
    __syncthreads();
    const float invN = 1.0f / (float)NPTS;
    float m[13], vr[13];
    for (int j = 0; j < 4; j++)  { m[j] = st[j] * invN;   vr[j] = st[4+j] * invN - m[j]*m[j]; }
    for (int j = 4; j < 7; j++)  { m[j] = 0.f;            vr[j] = st[j] * invN - st[16+j] * invN; }
    for (int j = 7; j < 10; j++) { m[j] = st[1+j] * invN; vr[j] = st[4+j] * invN - m[j]*m[j]; }
    for (int j = 10; j < 13; j++){ m[j] = st[4+j] * invN; vr[j] = st[7+j] * invN - m[j]*m[j]; }
    float bacc = b1[t];
    for (int j = 0; j < 13; j++) {
        float s = bn0g[j] * rsqrtf(vr[j] + EPSV);
        float tt = bn0b[j] - m[j] * s;
        Wf[j*64 + t] = s * w1[j*64 + t];
        bacc += tt * w1[j*64 + t];
    }
    bfv[t] = bacc;
}

// ---------------- BN1 stats (layer-1 only) ----------------
__global__ __launch_bounds__(256, 4) void k2b_stats1(
    const float4* __restrict__ pts, const float* __restrict__ nor,
    const int* __restrict__ gind, const int* __restrict__ cinv,
    const float4* __restrict__ vox4,
    const float* __restrict__ Wfp, const float* __restrict__ bfv,
    float* __restrict__ PH, float* __restrict__ PQ)
{
    int lane = threadIdx.x & 63;
    int w = threadIdx.x >> 6;
    int wid = blockIdx.x * 4 + w;
    int p0 = wid * W1CH, p1 = min(p0 + W1CH, NPTS);
    REP13(DECL_W1)
    float bc = bfv[lane];
    float sh = 0.f, sq = 0.f;
    for (int p = p0; p < p1; p++) {
        FEAT_GATHER
        float a = L1EXPR;
        sh += a; sq += a * a;
    }
    __shared__ float LH[4][64], LQ[4][64];
    LH[w][lane] = sh; LQ[w][lane] = sq;
    __syncthreads();
    if (w == 0) {
        PH[blockIdx.x * 64 + lane] = LH[0][lane] + LH[1][lane] + LH[2][lane] + LH[3][lane];
        PQ[blockIdx.x * 64 + lane] = LQ[0][lane] + LQ[1][lane] + LQ[2][lane] + LQ[3][lane];
    }
}

// ---------------- reduce + fold BN1 ----------------
__global__ __launch_bounds__(256) void k3c_fold(
    const float* __restrict__ PH, const float* __restrict__ PQ,
    const float* __restrict__ bn1g, const float* __restrict__ bn1b,
    const float* __restrict__ Wf, const float* __restrict__ bfv,
    float* __restrict__ Wf2, float* __restrict__ bf2)
{
    __shared__ float LH[4][64], LQ[4][64];
    int c = threadIdx.x & 63, g = threadIdx.x >> 6;
    float sH = 0.f, sQ = 0.f;
    for (int b = g; b < KB1; b += 4) { sH += PH[b*64 + c]; sQ += PQ[b*64 + c]; }
    LH[g][c] = sH; LQ[g][c] = sQ;
    __syncthreads();
    if (g == 0) {
        const float invN = 1.0f / (float)NPTS;
        float mn = (LH[0][c] + LH[1][c] + LH[2][c] + LH[3][c]) * invN;
        float vr = (LQ[0][c] + LQ[1][c] + LQ[2][c] + LQ[3][c]) * invN - mn * mn;
        float s = bn1g[c] * rsqrtf(vr + EPSV);
        float t = bn1b[c] - mn * s;
        for (int j = 0; j < 13; j++) Wf2[j*64 + c] = s * Wf[j*64 + c];
        bf2[c] = s * bfv[c] + t;
    }
}

// ---------------- BN2 stats (layer 1+2) ----------------
__global__ __launch_bounds__(256, 3) void k4_stats2(
    const float4* __restrict__ pts, const float* __restrict__ nor,
    const int* __restrict__ gind, const int* __restrict__ cinv,
    const float4* __restrict__ vox4,
    const float* __restrict__ Wfp, const float* __restrict__ bfv,
    const float* __restrict__ w2, const float* __restrict__ b2,
    float* __restrict__ PH, float* __restrict__ PQ)
{
    int lane = threadIdx.x & 63;
    int w = threadIdx.x >> 6;
    int wid = blockIdx.x * 4 + w;
    int p0 = wid * W2CH, p1 = min(p0 + W2CH, NPTS);
    REP13(DECL_W1)
    float bc = bfv[lane];
    REP64(DECL_W2)
    float b2c = b2[lane];
    float sh = 0.f, sq = 0.f;
    for (int p = p0; p < p1; p++) {
        FEAT_GATHER
        float r = fmaxf(L1EXPR, 0.f);
        float ha = b2c, hb = 0.f, hc = 0.f, hd = 0.f;
        L2ALL
        float h = (ha + hb) + (hc + hd);
        sh += h; sq += h * h;
    }
    __shared__ float LH[4][64], LQ[4][64];
    LH[w][lane] = sh; LQ[w][lane] = sq;
    __syncthreads();
    if (w == 0) {
        PH[blockIdx.x * 64 + lane] = LH[0][lane] + LH[1][lane] + LH[2][lane] + LH[3][lane];
        PQ[blockIdx.x * 64 + lane] = LQ[0][lane] + LQ[1][lane] + LQ[2][lane] + LQ[3][lane];
    }
}

// ---------------- reduce + finalize BN2 ----------------
__global__ __launch_bounds__(256) void k5_bn2(
    const float* __restrict__ PH, const float* __restrict__ PQ,
    const float* __restrict__ bn2g, const float* __restrict__ bn2b,
    float* __restrict__ s2, float* __restrict__ t2)
{
    __shared__ float LH[4][64], LQ[4][64];
    int c = threadIdx.x & 63, g = threadIdx.x >> 6;
    float sH = 0.f, sQ = 0.f;
    for (int b = g; b < KB2; b += 4) { sH += PH[b*64 + c]; sQ += PQ[b*64 + c]; }
    LH[g][c] = sH; LQ[g][c] = sQ;
    __syncthreads();
    if (g == 0) {
        const float invN = 1.0f / (float)NPTS;
        float mn = (LH[0][c] + LH[1][c] + LH[2][c] + LH[3][c]) * invN;
        float vr = (LQ[0][c] + LQ[1][c] + LQ[2][c] + LQ[3][c]) * invN - mn * mn;
        float s = bn2g[c] * rsqrtf(vr + EPSV);
        s2[c] = s; t2[c] = bn2b[c] - mn * s;
    }
}

// ---------------- main forward + per-voxel sum (wave per voxel, CSR) --------
__global__ __launch_bounds__(256, 3) void k6_gather(
    const float4* __restrict__ pts, const float* __restrict__ nor,
    const int* __restrict__ gind,
    const int* __restrict__ base, const int* __restrict__ pidx,
    const float4* __restrict__ vox4,
    const float* __restrict__ Wfp, const float* __restrict__ bfv,
    const float* __restrict__ w2, const float* __restrict__ b2,
    const float* __restrict__ s2, const float* __restrict__ t2,
    float* __restrict__ out)
{
    int lane = threadIdx.x & 63;
    int wid = blockIdx.x * 4 + (threadIdx.x >> 6);
    int v0 = wid * V6CH, v1 = min(v0 + V6CH, NVOX);
    REP13(DECL_W1)
    float bc = bfv[lane];
    REP64(DECL_W2)
    float b2c = b2[lane];
    float s2c = s2[lane], t2c = t2[lane];

    for (int v = v0; v < v1; v++) {
        int st = (v == 0) ? 0 : base[v - 1];
        int en = base[v];
        float4 vs = vox4[v];
        float accz = 0.f;
        for (int ii = st; ii < en; ii++) {
            int p = pidx[ii];
            FEAT_BODY
            float r = fmaxf(L1EXPR, 0.f);
            float ha = b2c, hb = 0.f, hc = 0.f, hd = 0.f;
            L2ALL
            float h = (ha + hb) + (hc + hd);
            accz += fmaxf(s2c * h + t2c, 0.f);
        }
        out[(size_t)v * 64 + lane] = accz;
    }
}

// ---------------- mean + w3 matmul + bias (in-place on d_out) ----------------
__global__ __launch_bounds__(256, 3) void k7_final(
    const float4* __restrict__ vox4, const float* __restrict__ w3,
    const float* __restrict__ b3, float* __restrict__ out)
{
    int lane = threadIdx.x & 63;
    int wid = blockIdx.x * 4 + (threadIdx.x >> 6);
    int v0 = wid * V7CH, v1 = min(v0 + V7CH, NVOX);
    REP64(DECL_W3)
    float b3c = b3[lane];
    for (int v = v0; v < v1; v++) {
        float cnt = vox4[v].w;
        float* row = out + (size_t)v * 64;
        if (cnt > 0.5f) {
            float m = row[lane] / cnt;
            float ya = b3c, yb = 0.f, yc = 0.f, yd = 0.f;
            L3ALL
            row[lane] = (ya + yb) + (yc + yd);
        } else {
            row[lane] = 0.f;
        }
    }
}

extern "C" void kernel_launch(void* const* d_in, const int* in_sizes, int n_in,
                              void* d_out, int out_size, void* d_ws, size_t ws_size,
                              hipStream_t stream) {
    const float4* pts  = (const float4*)d_in[0];
    const float*  nor  = (const float*)d_in[1];
    const int*    gind = (const int*)d_in[2];
    const int*    cinv = (const int*)d_in[3];
    const float*  bn0g = (const float*)d_in[4];
    const float*  bn0b = (const float*)d_in[5];
    const float*  w1   = (const float*)d_in[6];
    const float*  b1   = (const float*)d_in[7];
    const float*  bn1g = (const float*)d_in[8];
    const float*  bn1b = (const float*)d_in[9];
    const float*  w2   = (const float*)d_in[10];
    const float*  b2   = (const float*)d_in[11];
    const float*  bn2g = (const float*)d_in[12];
    const float*  bn2b = (const float*)d_in[13];
    const float*  w3   = (const float*)d_in[14];
    const float*  b3   = (const float*)d_in[15];

    float* ws    = (float*)d_ws;
    float* out   = (float*)d_out;
    int*   cnt   = (int*)(ws + OFF_CNT);
    int*   base  = (int*)(ws + OFF_BASE);
    int*   bsum  = (int*)(ws + OFF_BSUM);
    int*   boff  = (int*)(ws + OFF_BOFF);
    int*   pidx  = (int*)(ws + OFF_PIDX);
    float4* vox4 = (float4*)(ws + OFF_VOX);
    float* P0    = ws + OFF_P0;
    float* PM    = ws + OFF_PM;
    float* PH1   = ws + OFF_PH1;
    float* PQ1   = ws + OFF_PQ1;
    float* PH2   = ws + OFF_PH2;
    float* PQ2   = ws + OFF_PQ2;
    float* Wf    = ws + OFF_WF;
    float* bfv   = ws + OFF_BF;
    float* Wf2   = ws + OFF_WF2;
    float* bf2   = ws + OFF_BF2;
    float* s2    = ws + OFF_S2;
    float* t2    = ws + OFF_T2;

    hipMemsetAsync(d_ws, 0, (size_t)ZERO_WORDS * 4, stream);

    k_count<<<(NPTS + 255) / 256, 256, 0, stream>>>(cinv, cnt);
    k_scan1<<<NSCAN, SCAN_B, 0, stream>>>(cnt, base, bsum);
    k_scan2<<<1, SCAN_B, 0, stream>>>(bsum, boff);
    k_base<<<(NVOX + 255) / 256, 256, 0, stream>>>(boff, base);
    k_fill<<<(NPTS + 255) / 256, 256, 0, stream>>>(cinv, base, pidx);
    k_mean<<<NMB, 256, 0, stream>>>(pts, base, pidx, vox4, PM);
    k_stats0<<<SB0, 256, 0, stream>>>(pts, nor, gind, P0);
    k3b_fold<<<1, 64, 0, stream>>>(P0, PM, bn0g, bn0b, w1, b1, Wf, bfv);
    k2b_stats1<<<KB1, 256, 0, stream>>>(pts, nor, gind, cinv, vox4, Wf, bfv, PH1, PQ1);
    k3c_fold<<<1, 256, 0, stream>>>(PH1, PQ1, bn1g, bn1b, Wf, bfv, Wf2, bf2);
    k4_stats2<<<KB2, 256, 0, stream>>>(pts, nor, gind, cinv, vox4, Wf2, bf2, w2, b2, PH2, PQ2);
    k5_bn2<<<1, 256, 0, stream>>>(PH2, PQ2, bn2g, bn2b, s2, t2);
    k6_gather<<<KB6, 256, 0, stream>>>(pts, nor, gind, base, pidx, vox4,
                                       Wf2, bf2, w2, b2, s2, t2, out);
    k7_final<<<KB7, 256, 0, stream>>>(vox4, w3, b3, out);
}